// Round 1
// baseline (2130.944 us; speedup 1.0000x reference)
//
#include <hip/hip_runtime.h>
#include <math.h>

#define NN 50000
#define EE 800000
#define GG 512
#define HH 128
#define LL 3
#define OUTC 10
#define THR 0.01f
#define TM 128

__device__ __forceinline__ float elu_f(float x){ return x > 0.f ? x : (expf(x)-1.f); }

// ---------------- small setup kernels ----------------

__device__ void softmax_row(const float* in, float* out, int c){
    float m = in[0];
    for (int j=1;j<c;++j) m = fmaxf(m, in[j]);
    float s = 0.f;
    for (int j=0;j<c;++j){ float e = expf(in[j]-m); out[j]=e; s+=e; }
    for (int j=0;j<c;++j) out[j] /= s;
}

// coef layout: na[12] @0, pool[9] @12, ro[12] @21, la[3] @33
__global__ void prep_coef_k(const float* __restrict__ na, const float* __restrict__ pl,
                            const float* __restrict__ ro, const float* __restrict__ la,
                            float* __restrict__ coef){
    if (threadIdx.x != 0 || blockIdx.x != 0) return;
    for (int i=0;i<LL;++i)   softmax_row(na + i*4, coef + i*4, 4);
    for (int i=0;i<LL;++i)   softmax_row(pl + i*3, coef + 12 + i*3, 3);
    for (int i=0;i<LL+1;++i) softmax_row(ro + i*3, coef + 21 + i*3, 3);
    softmax_row(la, coef + 33, 3);
}

// Wc[i][0] = a1*W2 + a2*W3 + a3*W4 (for h), Wc[i][1] = a2*W3 + a3*W5 (for s_agg),
// Wc[i][2] = a1*W1 (for s_agg/deg)
__global__ __launch_bounds__(256) void combW_k(const float* __restrict__ gW,
                                               const float* __restrict__ coef,
                                               float* __restrict__ Wc){
    int idx = blockIdx.x*256 + threadIdx.x;
    if (idx >= LL*HH*HH) return;
    int i = idx >> 14;          // / 16384
    int j = idx & 16383;
    const float* W = gW + (size_t)i*6*16384;
    float a1 = coef[i*4+1], a2 = coef[i*4+2], a3 = coef[i*4+3];
    float w1 = W[1*16384+j], w2 = W[2*16384+j], w3 = W[3*16384+j],
          w4 = W[4*16384+j], w5 = W[5*16384+j];
    Wc[(size_t)(i*3+0)*16384 + j] = a1*w2 + a2*w3 + a3*w4;
    Wc[(size_t)(i*3+1)*16384 + j] = a2*w3 + a3*w5;
    Wc[(size_t)(i*3+2)*16384 + j] = a1*w1;
}

__global__ void count_k(const int* __restrict__ dst, int* __restrict__ counts){
    int e = blockIdx.x*256 + threadIdx.x;
    if (e < EE) atomicAdd(&counts[dst[e]], 1);
}

__global__ void scan_k(const int* __restrict__ counts, int* __restrict__ row_ptr){
    __shared__ int part[256];
    __shared__ int pref[257];
    int t = threadIdx.x;
    const int chunk = (NN + 255) / 256;
    int b = t*chunk, e = b + chunk; if (e > NN) e = NN; if (b > NN) b = NN;
    int s = 0;
    for (int n=b;n<e;++n) s += counts[n];
    part[t] = s;
    __syncthreads();
    if (t == 0){
        int a = 0;
        for (int i=0;i<256;++i){ pref[i] = a; a += part[i]; }
        pref[256] = a;
    }
    __syncthreads();
    int run = pref[t];
    for (int n=b;n<e;++n){ row_ptr[n] = run; run += counts[n]; }
    if (t == 0) row_ptr[NN] = pref[256];
}

__global__ void copy_int_k(const int* __restrict__ a, int* __restrict__ b, int n){
    int i = blockIdx.x*256 + threadIdx.x;
    if (i < n) b[i] = a[i];
}

__global__ void initf_k(float* __restrict__ a, float v, int n){
    int i = blockIdx.x*256 + threadIdx.x;
    if (i < n) a[i] = v;
}

__global__ void fill_k(const int* __restrict__ src, const int* __restrict__ dst,
                       int* __restrict__ cursor, int* __restrict__ csr_src){
    int e = blockIdx.x*256 + threadIdx.x;
    if (e < EE){
        int p = atomicAdd(&cursor[dst[e]], 1);
        csr_src[p] = src[e];
    }
}

__global__ void gstart_k(const int* __restrict__ batch, int* __restrict__ gstart){
    int g = blockIdx.x*256 + threadIdx.x;
    if (g > GG) return;
    if (g == GG){ gstart[GG] = NN; return; }
    int lo = 0, hi = NN;
    while (lo < hi){
        int mid = (lo + hi) >> 1;
        if (batch[mid] < g) lo = mid + 1; else hi = mid;
    }
    gstart[g] = lo;
}

// ---------------- GEMM: C[M,128] (+)= (A ⊙ rowscale)[M,128] @ B[128,128] ----------------
// flags bit0: accumulate into C; bit1: apply ELU; bias added if non-null.
__global__ __launch_bounds__(256) void gemm_k(const float* __restrict__ A,
                                              const float* __restrict__ B,
                                              float* __restrict__ C, int M,
                                              const float* __restrict__ rowscale,
                                              const float* __restrict__ bias, int flags){
    __shared__ float Bs[128][128];      // 64 KB
    __shared__ float As[128][TM+4];     // transposed A tile [k][r], 67.6 KB
    int tid = threadIdx.x;
    int row0 = blockIdx.x * TM;

    const float4* B4 = (const float4*)B;
    float4* Bs4 = (float4*)&Bs[0][0];
    #pragma unroll
    for (int i=0;i<16;++i) Bs4[tid + 256*i] = B4[tid + 256*i];

    for (int idx = tid; idx < TM*32; idx += 256){
        int r = idx >> 5, c = idx & 31;
        int gr = row0 + r;
        float4 v = make_float4(0.f,0.f,0.f,0.f);
        if (gr < M){
            v = ((const float4*)A)[(size_t)gr*32 + c];
            if (rowscale){ float s = rowscale[gr]; v.x*=s; v.y*=s; v.z*=s; v.w*=s; }
        }
        As[4*c+0][r] = v.x; As[4*c+1][r] = v.y; As[4*c+2][r] = v.z; As[4*c+3][r] = v.w;
    }
    __syncthreads();

    int cg = tid & 15;   // col group: cols cg*8..+7
    int rg = tid >> 4;   // row group: rows rg*8..+7
    float acc[8][8];
    #pragma unroll
    for (int r=0;r<8;++r)
        #pragma unroll
        for (int c=0;c<8;++c) acc[r][c] = 0.f;

    #pragma unroll 4
    for (int k=0;k<128;++k){
        float bv[8], av[8];
        #pragma unroll
        for (int c=0;c<8;++c) bv[c] = Bs[k][cg*8+c];
        #pragma unroll
        for (int r=0;r<8;++r) av[r] = As[k][rg*8+r];
        #pragma unroll
        for (int r=0;r<8;++r)
            #pragma unroll
            for (int c=0;c<8;++c) acc[r][c] = fmaf(av[r], bv[c], acc[r][c]);
    }

    for (int r=0;r<8;++r){
        int gr = row0 + rg*8 + r;
        if (gr >= M) continue;
        float* Crow = C + (size_t)gr*128 + cg*8;
        #pragma unroll
        for (int c=0;c<8;++c){
            float v = acc[r][c];
            if (bias) v += bias[cg*8+c];
            if (flags & 1) v += Crow[c];
            if (flags & 2) v = elu_f(v);
            Crow[c] = v;
        }
    }
}

// ---------------- per-layer graph kernels ----------------

__global__ void deg_k(const int* __restrict__ row_ptr, const int* __restrict__ csr_src,
                      const float* __restrict__ alive, float* __restrict__ rsd,
                      float* __restrict__ invdeg){
    int n = blockIdx.x*256 + threadIdx.x;
    if (n >= NN) return;
    float al = alive[n];
    float d;
    if (al == 0.f) d = 1e-6f;
    else {
        float s = 1.f;                      // self loop (alive)
        int e1 = row_ptr[n+1];
        for (int e = row_ptr[n]; e < e1; ++e) s += alive[csr_src[e]];
        d = fmaxf(s, 1e-6f);
    }
    rsd[n] = rsqrtf(d);
    invdeg[n] = 1.f / d;
}

// one wave per node: s_agg[n] = alive[n]*(sum alive[s]*h[s] + h[n])
//                    acc[n]   = a0*alive[n]*rsd[n]*(sum alive[s]*rsd[s]*hg[s] + rsd[n]*hg[n])
__global__ __launch_bounds__(256) void agg_k(const float* __restrict__ h, const float* __restrict__ hg,
                                             const int* __restrict__ row_ptr, const int* __restrict__ csr_src,
                                             const float* __restrict__ alive, const float* __restrict__ rsd,
                                             const float* __restrict__ coef_a0,
                                             float* __restrict__ s_agg, float* __restrict__ acc){
    int n = (blockIdx.x*256 + threadIdx.x) >> 6;
    int lane = threadIdx.x & 63;
    if (n >= NN) return;
    float2* sout = (float2*)(s_agg + (size_t)n*HH);
    float2* gout = (float2*)(acc + (size_t)n*HH);
    float al = alive[n];
    if (al == 0.f){
        sout[lane] = make_float2(0.f,0.f);
        gout[lane] = make_float2(0.f,0.f);
        return;
    }
    float a0 = *coef_a0;
    float rn = rsd[n];
    int e1 = row_ptr[n+1];
    float sx=0.f, sy=0.f, gx=0.f, gy=0.f;
    for (int e = row_ptr[n]; e < e1; ++e){
        int s = csr_src[e];
        float as = alive[s];
        if (as == 0.f) continue;
        float rs_ = rsd[s];
        float2 hv = ((const float2*)(h  + (size_t)s*HH))[lane];
        float2 gv = ((const float2*)(hg + (size_t)s*HH))[lane];
        sx += hv.x; sy += hv.y;
        gx = fmaf(rs_, gv.x, gx); gy = fmaf(rs_, gv.y, gy);
    }
    float2 hn = ((const float2*)(h  + (size_t)n*HH))[lane];
    float2 gn = ((const float2*)(hg + (size_t)n*HH))[lane];
    sx += hn.x; sy += hn.y;
    gx = fmaf(rn, gn.x, gx); gy = fmaf(rn, gn.y, gy);
    float cgc = a0 * rn;
    sout[lane] = make_float2(sx, sy);
    gout[lane] = make_float2(cgc*gx, cgc*gy);
}

// elu(acc) -> h, accumulate global sum/sumsq (f64) for full-tensor LayerNorm
__global__ __launch_bounds__(256) void elu_stats_k(const float* __restrict__ acc,
                                                   float* __restrict__ h,
                                                   double* __restrict__ stats){
    const int total = NN*HH;
    float ls = 0.f, lq = 0.f;
    for (int i = blockIdx.x*256 + threadIdx.x; i < total; i += gridDim.x*256){
        float e = elu_f(acc[i]);
        h[i] = e;
        ls += e;
        lq = fmaf(e, e, lq);
    }
    double s = ls, q = lq;
    #pragma unroll
    for (int o=32;o>0;o>>=1){ s += __shfl_xor(s,o,64); q += __shfl_xor(q,o,64); }
    __shared__ double sw[4], qw[4];
    int w = threadIdx.x >> 6;
    if ((threadIdx.x & 63) == 0){ sw[w] = s; qw[w] = q; }
    __syncthreads();
    if (threadIdx.x == 0){
        double S = sw[0]+sw[1]+sw[2]+sw[3];
        double Q = qw[0]+qw[1]+qw[2]+qw[3];
        atomicAdd(&stats[0], S);
        atomicAdd(&stats[1], Q);
    }
}

// LayerNorm (full-tensor) + gate pooling, one wave per node
__global__ __launch_bounds__(256) void ln_pool_k(float* __restrict__ h,
                                                 const double* __restrict__ stats,
                                                 const float* __restrict__ p0,
                                                 const float* __restrict__ p1,
                                                 const float* __restrict__ pa,
                                                 float* __restrict__ alive){
    int n = (blockIdx.x*256 + threadIdx.x) >> 6;
    int lane = threadIdx.x & 63;
    if (n >= NN) return;
    const double tot = (double)NN * (double)HH;
    double m = stats[0] / tot;
    double var = stats[1] / tot - m*m;
    float mf = (float)m;
    float rs = rsqrtf((float)var + 1e-5f);
    float2 v = ((float2*)(h + (size_t)n*HH))[lane];
    v.x = (v.x - mf)*rs; v.y = (v.y - mf)*rs;
    float2 q0 = ((const float2*)p0)[lane];
    float2 q1 = ((const float2*)p1)[lane];
    float d0 = v.x*q0.x + v.y*q0.y;
    float d1 = v.x*q1.x + v.y*q1.y;
    #pragma unroll
    for (int o=32;o>0;o>>=1){ d0 += __shfl_xor(d0,o,64); d1 += __shfl_xor(d1,o,64); }
    float g1 = 1.f/(1.f + expf(-d0));
    float g2 = tanhf(d1);
    float gate = pa[0]*g1 + pa[1]*g2 + pa[2];
    float keep = gate > THR ? 1.f : 0.f;
    float sc = gate*keep;
    v.x *= sc; v.y *= sc;
    ((float2*)(h + (size_t)n*HH))[lane] = v;
    if (lane == 0) alive[n] *= keep;
}

// mixed readout per graph: w0*mean + w1*max + w2*sum
__global__ __launch_bounds__(128) void readout_k(const float* __restrict__ h,
                                                 const int* __restrict__ gstart,
                                                 const float* __restrict__ w,
                                                 float* __restrict__ rep){
    int g = blockIdx.x, t = threadIdx.x;
    int beg = gstart[g], end = gstart[g+1];
    float sum = 0.f, mx = -INFINITY;
    for (int n = beg; n < end; ++n){
        float v = h[(size_t)n*HH + t];
        sum += v;
        mx = fmaxf(mx, v);
    }
    float cnt = (float)(end - beg);
    float mean = sum / fmaxf(cnt, 1.f);
    if (end <= beg) mx = 0.f;
    rep[(size_t)g*HH + t] = w[0]*mean + w[1]*mx + w[2]*sum;
}

__global__ __launch_bounds__(128) void final_k(const float* __restrict__ reps,
                                               const float* __restrict__ la,
                                               const float* __restrict__ loW,
                                               const float* __restrict__ lob,
                                               const float* __restrict__ cW,
                                               const float* __restrict__ cb,
                                               float* __restrict__ out){
    int g = blockIdx.x, t = threadIdx.x;
    float r0 = reps[(size_t)(0*GG+g)*HH + t];
    float r1 = reps[(size_t)(1*GG+g)*HH + t];
    float r2 = reps[(size_t)(2*GG+g)*HH + t];
    float r3 = reps[(size_t)(3*GG+g)*HH + t];
    float s = r0+r1+r2+r3;
    float mean = 0.25f*s;
    float mx = fmaxf(fmaxf(r0,r1), fmaxf(r2,r3));
    float z = la[0]*elu_f(s) + la[1]*elu_f(mean) + la[2]*elu_f(mx);
    __shared__ float zs[HH];
    zs[t] = z;
    __syncthreads();
    float a = lob[t];
    for (int k=0;k<HH;++k) a = fmaf(zs[k], loW[(size_t)k*HH + t], a);
    float z2 = elu_f(a);
    __shared__ float z2s[HH];
    z2s[t] = z2;
    __syncthreads();
    __shared__ float lg[OUTC];
    if (t < OUTC){
        float acc = cb[t];
        for (int k=0;k<HH;++k) acc = fmaf(z2s[k], cW[(size_t)k*OUTC + t], acc);
        lg[t] = acc;
    }
    __syncthreads();
    if (t == 0){
        float m = lg[0];
        for (int o=1;o<OUTC;++o) m = fmaxf(m, lg[o]);
        float se = 0.f;
        for (int o=0;o<OUTC;++o) se += expf(lg[o]-m);
        float lse = m + logf(se);
        for (int o=0;o<OUTC;++o) out[(size_t)g*OUTC + o] = lg[o] - lse;
    }
}

// ---------------- host launch ----------------

extern "C" void kernel_launch(void* const* d_in, const int* in_sizes, int n_in,
                              void* d_out, int out_size, void* d_ws, size_t ws_size,
                              hipStream_t stream){
    const float* x     = (const float*)d_in[0];
    const int*   ei    = (const int*)d_in[1];
    const int*   batch = (const int*)d_in[2];
    const float* l1W   = (const float*)d_in[3];
    const float* l1b   = (const float*)d_in[4];
    const float* gW    = (const float*)d_in[5];
    const float* poolp = (const float*)d_in[6];
    const float* loW   = (const float*)d_in[7];
    const float* lob   = (const float*)d_in[8];
    const float* cW    = (const float*)d_in[9];
    const float* cb    = (const float*)d_in[10];
    const float* nalog = (const float*)d_in[11];
    const float* pllog = (const float*)d_in[12];
    const float* rolog = (const float*)d_in[13];
    const float* lalog = (const float*)d_in[14];
    float* out = (float*)d_out;

    char* wsb = (char*)d_ws;
    size_t off = 0;
    auto alloc = [&](size_t bytes)->char* {
        char* p = wsb + off;
        off += (bytes + 255) & ~(size_t)255;
        return p;
    };
    float* h      = (float*)alloc(sizeof(float)*(size_t)NN*HH);
    float* hg     = (float*)alloc(sizeof(float)*(size_t)NN*HH);
    float* sagg   = (float*)alloc(sizeof(float)*(size_t)NN*HH);
    float* acc    = (float*)alloc(sizeof(float)*(size_t)NN*HH);
    float* Wc     = (float*)alloc(sizeof(float)*(size_t)LL*3*HH*HH);
    int*   row_ptr= (int*)alloc(sizeof(int)*(NN+1));
    int*   counts = (int*)alloc(sizeof(int)*NN);
    int*   cursor = (int*)alloc(sizeof(int)*NN);
    int*   csr_src= (int*)alloc(sizeof(int)*EE);
    float* rsd    = (float*)alloc(sizeof(float)*NN);
    float* invdeg = (float*)alloc(sizeof(float)*NN);
    float* alive  = (float*)alloc(sizeof(float)*NN);
    int*   gstart = (int*)alloc(sizeof(int)*(GG+1));
    float* reps   = (float*)alloc(sizeof(float)*(size_t)(LL+1)*GG*HH);
    float* coef   = (float*)alloc(sizeof(float)*64);
    double* stats = (double*)alloc(sizeof(double)*2*LL);

    const int* srcp = ei;
    const int* dstp = ei + EE;

    hipMemsetAsync(counts, 0, sizeof(int)*NN, stream);
    hipMemsetAsync(stats, 0, sizeof(double)*2*LL, stream);

    prep_coef_k<<<1, 64, 0, stream>>>(nalog, pllog, rolog, lalog, coef);
    combW_k<<<(LL*HH*HH + 255)/256, 256, 0, stream>>>(gW, coef, Wc);
    count_k<<<(EE + 255)/256, 256, 0, stream>>>(dstp, counts);
    scan_k<<<1, 256, 0, stream>>>(counts, row_ptr);
    copy_int_k<<<(NN + 255)/256, 256, 0, stream>>>(row_ptr, cursor, NN);
    fill_k<<<(EE + 255)/256, 256, 0, stream>>>(srcp, dstp, cursor, csr_src);
    gstart_k<<<(GG + 256)/256, 256, 0, stream>>>(batch, gstart);
    initf_k<<<(NN + 255)/256, 256, 0, stream>>>(alive, 1.f, NN);

    const int gemm_blocks = (NN + TM - 1)/TM;

    // h = elu(x @ lin1_W + lin1_b)
    gemm_k<<<gemm_blocks, 256, 0, stream>>>(x, l1W, h, NN, nullptr, l1b, 2);
    readout_k<<<GG, HH, 0, stream>>>(h, gstart, coef + 21, reps);

    for (int i=0;i<LL;++i){
        gemm_k<<<gemm_blocks, 256, 0, stream>>>(h, gW + (size_t)i*6*HH*HH, hg, NN, nullptr, nullptr, 0);
        deg_k<<<(NN + 255)/256, 256, 0, stream>>>(row_ptr, csr_src, alive, rsd, invdeg);
        agg_k<<<(NN + 3)/4, 256, 0, stream>>>(h, hg, row_ptr, csr_src, alive, rsd, coef + i*4, sagg, acc);
        gemm_k<<<gemm_blocks, 256, 0, stream>>>(h,    Wc + (size_t)(i*3+0)*HH*HH, acc, NN, nullptr, nullptr, 1);
        gemm_k<<<gemm_blocks, 256, 0, stream>>>(sagg, Wc + (size_t)(i*3+1)*HH*HH, acc, NN, nullptr, nullptr, 1);
        gemm_k<<<gemm_blocks, 256, 0, stream>>>(sagg, Wc + (size_t)(i*3+2)*HH*HH, acc, NN, invdeg, nullptr, 1);
        elu_stats_k<<<1024, 256, 0, stream>>>(acc, h, stats + 2*i);
        ln_pool_k<<<(NN + 3)/4, 256, 0, stream>>>(h, stats + 2*i,
                                                  poolp + (size_t)(i*2+0)*HH,
                                                  poolp + (size_t)(i*2+1)*HH,
                                                  coef + 12 + i*3, alive);
        readout_k<<<GG, HH, 0, stream>>>(h, gstart, coef + 21 + (i+1)*3, reps + (size_t)(i+1)*GG*HH);
    }

    final_k<<<GG, HH, 0, stream>>>(reps, coef + 33, loW, lob, cW, cb, out);
}

// Round 2
// 953.839 us; speedup vs baseline: 2.2341x; 2.2341x over previous
//
#include <hip/hip_runtime.h>
#include <math.h>

#define NN 50000
#define EE 800000
#define GG 512
#define HH 128
#define LL 3
#define OUTC 10
#define THR 0.01f

typedef unsigned short u16;
typedef unsigned int u32;
typedef __attribute__((ext_vector_type(8))) short short8;
typedef __attribute__((ext_vector_type(4))) float f32x4;

__device__ __forceinline__ float elu_f(float x){ return x > 0.f ? x : (expf(x)-1.f); }
__device__ __forceinline__ u16 f2bf(float f){
    u32 u = __float_as_uint(f);
    return (u16)((u + 0x7fffu + ((u>>16)&1u)) >> 16);
}
__device__ __forceinline__ float bf2f(u16 b){ return __uint_as_float(((u32)b)<<16); }
__device__ __forceinline__ u32 pack2(float a, float b){
    return (u32)f2bf(a) | ((u32)f2bf(b)<<16);
}

// ---------------- setup kernels ----------------

__device__ void softmax_row(const float* in, float* out, int c){
    float m = in[0];
    for (int j=1;j<c;++j) m = fmaxf(m, in[j]);
    float s = 0.f;
    for (int j=0;j<c;++j){ float e = expf(in[j]-m); out[j]=e; s+=e; }
    for (int j=0;j<c;++j) out[j] /= s;
}

// coef layout: na[12] @0, pool[9] @12, ro[12] @21, la[3] @33
__global__ void prep_coef_k(const float* __restrict__ na, const float* __restrict__ pl,
                            const float* __restrict__ ro, const float* __restrict__ la,
                            float* __restrict__ coef){
    if (threadIdx.x != 0 || blockIdx.x != 0) return;
    for (int i=0;i<LL;++i)   softmax_row(na + i*4, coef + i*4, 4);
    for (int i=0;i<LL;++i)   softmax_row(pl + i*3, coef + 12 + i*3, 3);
    for (int i=0;i<LL+1;++i) softmax_row(ro + i*3, coef + 21 + i*3, 3);
    softmax_row(la, coef + 33, 3);
}

// Build per-layer combined B stacks, bf16, TRANSPOSED to [n][k]:
// B0 = a1*W2+a2*W3+a3*W4 (h), B1 = a2*W3+a3*W5 (sagg), B2 = a1*W1 (sagg/deg), B3 = a0*W0 (gagg)
// gnn_W order: [W0 gcn, W1 sage_n, W2 sage_s, W3 gin, W4 gconv_s, W5 gconv_n]
__global__ __launch_bounds__(256) void prep_w_k(const float* __restrict__ gW,
                                                const float* __restrict__ lin1W,
                                                const float* __restrict__ coef,
                                                u16* __restrict__ Wc, u16* __restrict__ lin1t){
    int idx = blockIdx.x*256 + threadIdx.x;
    const int total = LL*4*16384;
    if (idx < total){
        int i = idx >> 16;          // 4*16384
        int rem = idx & 65535;
        int p = rem >> 14;
        int j = rem & 16383;
        int n = j >> 7, k = j & 127;
        const float* W = gW + (size_t)i*6*16384;
        float a0=coef[i*4], a1=coef[i*4+1], a2=coef[i*4+2], a3=coef[i*4+3];
        int e = k*128 + n;
        float v;
        if (p==0)      v = a1*W[2*16384+e] + a2*W[3*16384+e] + a3*W[4*16384+e];
        else if (p==1) v = a2*W[3*16384+e] + a3*W[5*16384+e];
        else if (p==2) v = a1*W[1*16384+e];
        else           v = a0*W[0*16384+e];
        Wc[(size_t)(i*4+p)*16384 + n*128 + k] = f2bf(v);
    } else if (idx < total + 16384){
        int j = idx - total;
        int n = j >> 7, k = j & 127;
        lin1t[n*128 + k] = f2bf(lin1W[k*128 + n]);
    }
}

__global__ void x2bf_k(const float* __restrict__ x, u16* __restrict__ xb){
    int i = blockIdx.x*256 + threadIdx.x;
    if (i >= NN*HH/8) return;
    const float4* p = (const float4*)x + (size_t)i*2;
    float4 v0 = p[0], v1 = p[1];
    uint4 o;
    o.x = pack2(v0.x, v0.y); o.y = pack2(v0.z, v0.w);
    o.z = pack2(v1.x, v1.y); o.w = pack2(v1.z, v1.w);
    ((uint4*)xb)[i] = o;
}

__global__ void count_k(const int* __restrict__ dst, int* __restrict__ counts){
    int e = blockIdx.x*256 + threadIdx.x;
    if (e < EE) atomicAdd(&counts[dst[e]], 1);
}

__global__ void scan_k(const int* __restrict__ counts, int* __restrict__ row_ptr){
    __shared__ int part[256];
    __shared__ int pref[257];
    int t = threadIdx.x;
    const int chunk = (NN + 255) / 256;
    int b = t*chunk, e = b + chunk; if (e > NN) e = NN; if (b > NN) b = NN;
    int s = 0;
    for (int n=b;n<e;++n) s += counts[n];
    part[t] = s;
    __syncthreads();
    if (t == 0){
        int a = 0;
        for (int i=0;i<256;++i){ pref[i] = a; a += part[i]; }
        pref[256] = a;
    }
    __syncthreads();
    int run = pref[t];
    for (int n=b;n<e;++n){ row_ptr[n] = run; run += counts[n]; }
    if (t == 0) row_ptr[NN] = pref[256];
}

__global__ void copy_int_k(const int* __restrict__ a, int* __restrict__ b, int n){
    int i = blockIdx.x*256 + threadIdx.x;
    if (i < n) b[i] = a[i];
}

__global__ void initf_k(float* __restrict__ a, float v, int n){
    int i = blockIdx.x*256 + threadIdx.x;
    if (i < n) a[i] = v;
}

__global__ void fill_k(const int* __restrict__ src, const int* __restrict__ dst,
                       int* __restrict__ cursor, int* __restrict__ csr_src){
    int e = blockIdx.x*256 + threadIdx.x;
    if (e < EE){
        int p = atomicAdd(&cursor[dst[e]], 1);
        csr_src[p] = src[e];
    }
}

__global__ void gstart_k(const int* __restrict__ batch, int* __restrict__ gstart){
    int g = blockIdx.x*256 + threadIdx.x;
    if (g > GG) return;
    if (g == GG){ gstart[GG] = NN; return; }
    int lo = 0, hi = NN;
    while (lo < hi){
        int mid = (lo + hi) >> 1;
        if (batch[mid] < g) lo = mid + 1; else hi = mid;
    }
    gstart[g] = lo;
}

// ---------------- fused MFMA GEMM ----------------
// C[M,128] = sum_p A_p[M,128] @ B_p, A bf16 [row][k], B bf16 TRANSPOSED [n][k].
// FLAGS&1: elu + f32 out + LN stats (f64 atomics). FLAGS&2: bias + elu + bf16 out.
template<int FLAGS, int NP>
__global__ __launch_bounds__(256) void mm_k(
    const u16* __restrict__ A0, const u16* __restrict__ A1,
    const u16* __restrict__ A2, const u16* __restrict__ A3,
    const u16* __restrict__ Bb, const float* __restrict__ rowscale,
    const float* __restrict__ bias,
    float* __restrict__ Cf, u16* __restrict__ Cbf,
    double* __restrict__ stats, int M)
{
    __shared__ u16 As[128*128];   // 32 KB, XOR-swizzled in 16B groups
    __shared__ u16 Bs[128*128];   // 32 KB
    int tid = threadIdx.x;
    int w = tid >> 6, l = tid & 63;
    int row0 = blockIdx.x * 128;

    f32x4 acc[2][8];
    #pragma unroll
    for (int rt=0;rt<2;++rt)
        #pragma unroll
        for (int ct=0;ct<8;++ct) acc[rt][ct] = (f32x4){0.f,0.f,0.f,0.f};

    auto do_pair = [&](const u16* __restrict__ Ap, const u16* __restrict__ Bp, bool dors){
        __syncthreads();
        #pragma unroll
        for (int it=0; it<8; ++it){
            int r = it*16 + (tid>>4);
            int g = tid & 15;
            int gr = row0 + r;
            uint4 av = make_uint4(0u,0u,0u,0u);
            if (gr < M){
                av = *(const uint4*)(Ap + (size_t)gr*128 + g*8);
                if (dors){
                    float s = rowscale[gr];
                    u32* pv = (u32*)&av;
                    #pragma unroll
                    for (int j2=0;j2<4;++j2){
                        u32 t2 = pv[j2];
                        pv[j2] = pack2(bf2f((u16)(t2&0xffffu))*s, bf2f((u16)(t2>>16))*s);
                    }
                }
            }
            *(uint4*)(As + r*128 + ((g ^ (r&7))<<3)) = av;
            uint4 bv = *(const uint4*)(Bp + r*128 + g*8);
            *(uint4*)(Bs + r*128 + ((g ^ (r&7))<<3)) = bv;
        }
        __syncthreads();
        #pragma unroll
        for (int ks=0; ks<4; ++ks){
            int kq = ks*4 + (l>>4);
            short8 a[2], b[8];
            #pragma unroll
            for (int rt=0; rt<2; ++rt){
                int r = w*32 + rt*16 + (l&15);
                a[rt] = *(const short8*)(As + r*128 + ((kq ^ (r&7))<<3));
            }
            #pragma unroll
            for (int ct=0; ct<8; ++ct){
                int r = ct*16 + (l&15);
                b[ct] = *(const short8*)(Bs + r*128 + ((kq ^ (r&7))<<3));
            }
            #pragma unroll
            for (int rt=0; rt<2; ++rt)
                #pragma unroll
                for (int ct=0; ct<8; ++ct)
                    acc[rt][ct] = __builtin_amdgcn_mfma_f32_16x16x32_bf16(a[rt], b[ct], acc[rt][ct], 0, 0, 0);
        }
    };

    do_pair(A0, Bb, false);
    if constexpr (NP == 4){
        do_pair(A1, Bb + 16384, false);
        do_pair(A2, Bb + 2*16384, true);
        do_pair(A3, Bb + 3*16384, false);
    }

    float ls = 0.f, lq = 0.f;
    float bcol[8];
    if constexpr (FLAGS & 2){
        #pragma unroll
        for (int ct=0; ct<8; ++ct) bcol[ct] = bias[ct*16 + (l&15)];
    }
    #pragma unroll
    for (int rt=0; rt<2; ++rt){
        #pragma unroll
        for (int i=0; i<4; ++i){
            int row = row0 + w*32 + rt*16 + (l>>4)*4 + i;
            if (row >= M) continue;
            #pragma unroll
            for (int ct=0; ct<8; ++ct){
                float v = acc[rt][ct][i];
                if constexpr (FLAGS & 2) v += bcol[ct];
                v = elu_f(v);
                int col = ct*16 + (l&15);
                if constexpr (FLAGS & 1){
                    Cf[(size_t)row*128 + col] = v;
                    ls += v; lq = fmaf(v, v, lq);
                } else {
                    Cbf[(size_t)row*128 + col] = f2bf(v);
                }
            }
        }
    }
    if constexpr (FLAGS & 1){
        double s = ls, q = lq;
        #pragma unroll
        for (int o=32;o>0;o>>=1){ s += __shfl_xor(s,o,64); q += __shfl_xor(q,o,64); }
        __shared__ double sw[4], qw[4];
        if (l == 0){ sw[w] = s; qw[w] = q; }
        __syncthreads();
        if (tid == 0){
            atomicAdd(&stats[0], sw[0]+sw[1]+sw[2]+sw[3]);
            atomicAdd(&stats[1], qw[0]+qw[1]+qw[2]+qw[3]);
        }
    }
}

// ---------------- per-layer graph kernels ----------------

__global__ void deg_k(const int* __restrict__ row_ptr, const int* __restrict__ csr_src,
                      const float* __restrict__ alive, float* __restrict__ rsd,
                      float* __restrict__ invdeg){
    int n = blockIdx.x*256 + threadIdx.x;
    if (n >= NN) return;
    float al = alive[n];
    float d;
    if (al == 0.f) d = 1e-6f;
    else {
        float s = 1.f;                      // self loop
        int e1 = row_ptr[n+1];
        for (int e = row_ptr[n]; e < e1; ++e) s += alive[csr_src[e]];
        d = fmaxf(s, 1e-6f);
    }
    rsd[n] = rsqrtf(d);
    invdeg[n] = 1.f / d;
}

// one wave per node, bf16 h gather:
// sagg[n] = sum_{alive s} h[s] + h[n];  gagg[n] = rsd[n]*(sum rsd[s]*h[s] + rsd[n]*h[n])
__global__ __launch_bounds__(256) void agg_k(const u16* __restrict__ h,
    const int* __restrict__ row_ptr, const int* __restrict__ csr_src,
    const float* __restrict__ alive, const float* __restrict__ rsd,
    u16* __restrict__ sagg, u16* __restrict__ gagg){
    int n = (blockIdx.x*256 + threadIdx.x) >> 6;
    int lane = threadIdx.x & 63;
    if (n >= NN) return;
    u32* so = (u32*)(sagg + (size_t)n*HH);
    u32* go = (u32*)(gagg + (size_t)n*HH);
    if (alive[n] == 0.f){ so[lane] = 0u; go[lane] = 0u; return; }
    float rn = rsd[n];
    int e1 = row_ptr[n+1];
    float sx=0.f, sy=0.f, gx=0.f, gy=0.f;
    for (int e = row_ptr[n]; e < e1; ++e){
        int s = csr_src[e];
        float as = alive[s];
        if (as == 0.f) continue;
        float rw = rsd[s];
        u32 hv = *(const u32*)(h + (size_t)s*HH + lane*2);
        float hx = bf2f((u16)(hv & 0xffffu)), hy = bf2f((u16)(hv >> 16));
        sx += hx; sy += hy;
        gx = fmaf(rw, hx, gx); gy = fmaf(rw, hy, gy);
    }
    u32 hv = *(const u32*)(h + (size_t)n*HH + lane*2);
    float hx = bf2f((u16)(hv & 0xffffu)), hy = bf2f((u16)(hv >> 16));
    sx += hx; sy += hy;
    gx = fmaf(rn, hx, gx); gy = fmaf(rn, hy, gy);
    so[lane] = pack2(sx, sy);
    go[lane] = pack2(rn*gx, rn*gy);
}

// full-tensor LayerNorm + gate pooling; reads f32 h (post-elu), writes bf16 h
__global__ __launch_bounds__(256) void ln_pool_k(const float* __restrict__ hf,
                                                 u16* __restrict__ hb,
                                                 const double* __restrict__ stats,
                                                 const float* __restrict__ p0,
                                                 const float* __restrict__ p1,
                                                 const float* __restrict__ pa,
                                                 float* __restrict__ alive){
    int n = (blockIdx.x*256 + threadIdx.x) >> 6;
    int lane = threadIdx.x & 63;
    if (n >= NN) return;
    const double tot = (double)NN * (double)HH;
    double m = stats[0] / tot;
    double var = stats[1] / tot - m*m;
    float mf = (float)m;
    float rs = rsqrtf((float)var + 1e-5f);
    float2 v = ((const float2*)(hf + (size_t)n*HH))[lane];
    v.x = (v.x - mf)*rs; v.y = (v.y - mf)*rs;
    float2 q0 = ((const float2*)p0)[lane];
    float2 q1 = ((const float2*)p1)[lane];
    float d0 = v.x*q0.x + v.y*q0.y;
    float d1 = v.x*q1.x + v.y*q1.y;
    #pragma unroll
    for (int o=32;o>0;o>>=1){ d0 += __shfl_xor(d0,o,64); d1 += __shfl_xor(d1,o,64); }
    float g1 = 1.f/(1.f + expf(-d0));
    float g2 = tanhf(d1);
    float gate = pa[0]*g1 + pa[1]*g2 + pa[2];
    float keep = gate > THR ? 1.f : 0.f;
    float sc = gate*keep;
    ((u32*)(hb + (size_t)n*HH))[lane] = pack2(v.x*sc, v.y*sc);
    if (lane == 0 && keep == 0.f) alive[n] = 0.f;
}

// mixed readout per graph from bf16 h
__global__ __launch_bounds__(128) void readout_k(const u16* __restrict__ h,
                                                 const int* __restrict__ gstart,
                                                 const float* __restrict__ w,
                                                 float* __restrict__ rep){
    int g = blockIdx.x, t = threadIdx.x;
    int beg = gstart[g], end = gstart[g+1];
    float sum = 0.f, mx = -INFINITY;
    for (int n = beg; n < end; ++n){
        float v = bf2f(h[(size_t)n*HH + t]);
        sum += v;
        mx = fmaxf(mx, v);
    }
    float cnt = (float)(end - beg);
    float mean = sum / fmaxf(cnt, 1.f);
    if (end <= beg) mx = 0.f;
    rep[(size_t)g*HH + t] = w[0]*mean + w[1]*mx + w[2]*sum;
}

__global__ __launch_bounds__(128) void final_k(const float* __restrict__ reps,
                                               const float* __restrict__ la,
                                               const float* __restrict__ loW,
                                               const float* __restrict__ lob,
                                               const float* __restrict__ cW,
                                               const float* __restrict__ cb,
                                               float* __restrict__ out){
    int g = blockIdx.x, t = threadIdx.x;
    float r0 = reps[(size_t)(0*GG+g)*HH + t];
    float r1 = reps[(size_t)(1*GG+g)*HH + t];
    float r2 = reps[(size_t)(2*GG+g)*HH + t];
    float r3 = reps[(size_t)(3*GG+g)*HH + t];
    float s = r0+r1+r2+r3;
    float mean = 0.25f*s;
    float mx = fmaxf(fmaxf(r0,r1), fmaxf(r2,r3));
    float z = la[0]*elu_f(s) + la[1]*elu_f(mean) + la[2]*elu_f(mx);
    __shared__ float zs[HH];
    zs[t] = z;
    __syncthreads();
    float a = lob[t];
    for (int k=0;k<HH;++k) a = fmaf(zs[k], loW[(size_t)k*HH + t], a);
    float z2 = elu_f(a);
    __shared__ float z2s[HH];
    z2s[t] = z2;
    __syncthreads();
    __shared__ float lg[OUTC];
    if (t < OUTC){
        float acc = cb[t];
        for (int k=0;k<HH;++k) acc = fmaf(z2s[k], cW[(size_t)k*OUTC + t], acc);
        lg[t] = acc;
    }
    __syncthreads();
    if (t == 0){
        float m = lg[0];
        for (int o=1;o<OUTC;++o) m = fmaxf(m, lg[o]);
        float se = 0.f;
        for (int o=0;o<OUTC;++o) se += expf(lg[o]-m);
        float lse = m + logf(se);
        for (int o=0;o<OUTC;++o) out[(size_t)g*OUTC + o] = lg[o] - lse;
    }
}

// ---------------- host launch ----------------

extern "C" void kernel_launch(void* const* d_in, const int* in_sizes, int n_in,
                              void* d_out, int out_size, void* d_ws, size_t ws_size,
                              hipStream_t stream){
    const float* x     = (const float*)d_in[0];
    const int*   ei    = (const int*)d_in[1];
    const int*   batch = (const int*)d_in[2];
    const float* l1W   = (const float*)d_in[3];
    const float* l1b   = (const float*)d_in[4];
    const float* gW    = (const float*)d_in[5];
    const float* poolp = (const float*)d_in[6];
    const float* loW   = (const float*)d_in[7];
    const float* lob   = (const float*)d_in[8];
    const float* cW    = (const float*)d_in[9];
    const float* cb    = (const float*)d_in[10];
    const float* nalog = (const float*)d_in[11];
    const float* pllog = (const float*)d_in[12];
    const float* rolog = (const float*)d_in[13];
    const float* lalog = (const float*)d_in[14];
    float* out = (float*)d_out;

    char* wsb = (char*)d_ws;
    size_t off = 0;
    auto alloc = [&](size_t bytes)->char* {
        char* p = wsb + off;
        off += (bytes + 255) & ~(size_t)255;
        return p;
    };
    float* hf     = (float*)alloc(sizeof(float)*(size_t)NN*HH);
    u16*   hb     = (u16*)alloc(sizeof(u16)*(size_t)NN*HH);
    u16*   xb     = (u16*)alloc(sizeof(u16)*(size_t)NN*HH);
    u16*   sagg   = (u16*)alloc(sizeof(u16)*(size_t)NN*HH);
    u16*   gagg   = (u16*)alloc(sizeof(u16)*(size_t)NN*HH);
    u16*   Wc     = (u16*)alloc(sizeof(u16)*(size_t)LL*4*HH*HH);
    u16*   lin1t  = (u16*)alloc(sizeof(u16)*HH*HH);
    int*   row_ptr= (int*)alloc(sizeof(int)*(NN+1));
    int*   counts = (int*)alloc(sizeof(int)*NN);
    int*   cursor = (int*)alloc(sizeof(int)*NN);
    int*   csr_src= (int*)alloc(sizeof(int)*EE);
    float* rsd    = (float*)alloc(sizeof(float)*NN);
    float* invdeg = (float*)alloc(sizeof(float)*NN);
    float* alive  = (float*)alloc(sizeof(float)*NN);
    int*   gstart = (int*)alloc(sizeof(int)*(GG+1));
    float* reps   = (float*)alloc(sizeof(float)*(size_t)(LL+1)*GG*HH);
    float* coef   = (float*)alloc(sizeof(float)*64);
    double* stats = (double*)alloc(sizeof(double)*2*LL);

    const int* srcp = ei;
    const int* dstp = ei + EE;

    hipMemsetAsync(counts, 0, sizeof(int)*NN, stream);
    hipMemsetAsync(stats, 0, sizeof(double)*2*LL, stream);

    prep_coef_k<<<1, 64, 0, stream>>>(nalog, pllog, rolog, lalog, coef);
    prep_w_k<<<(LL*4*16384 + 16384 + 255)/256, 256, 0, stream>>>(gW, l1W, coef, Wc, lin1t);
    count_k<<<(EE + 255)/256, 256, 0, stream>>>(dstp, counts);
    scan_k<<<1, 256, 0, stream>>>(counts, row_ptr);
    copy_int_k<<<(NN + 255)/256, 256, 0, stream>>>(row_ptr, cursor, NN);
    fill_k<<<(EE + 255)/256, 256, 0, stream>>>(srcp, dstp, cursor, csr_src);
    gstart_k<<<(GG + 256)/256, 256, 0, stream>>>(batch, gstart);
    initf_k<<<(NN + 255)/256, 256, 0, stream>>>(alive, 1.f, NN);
    x2bf_k<<<(NN*HH/8 + 255)/256, 256, 0, stream>>>(x, xb);

    const int gemm_blocks = (NN + 127)/128;

    // h = elu(x @ lin1_W + b) -> bf16
    mm_k<2,1><<<gemm_blocks, 256, 0, stream>>>(xb, nullptr, nullptr, nullptr,
                                               lin1t, nullptr, l1b, nullptr, hb, nullptr, NN);
    readout_k<<<GG, HH, 0, stream>>>(hb, gstart, coef + 21, reps);

    for (int i=0;i<LL;++i){
        deg_k<<<(NN + 255)/256, 256, 0, stream>>>(row_ptr, csr_src, alive, rsd, invdeg);
        agg_k<<<(NN + 3)/4, 256, 0, stream>>>(hb, row_ptr, csr_src, alive, rsd, sagg, gagg);
        mm_k<1,4><<<gemm_blocks, 256, 0, stream>>>(hb, sagg, sagg, gagg,
                                                   Wc + (size_t)i*4*16384, invdeg, nullptr,
                                                   hf, nullptr, stats + 2*i, NN);
        ln_pool_k<<<(NN + 3)/4, 256, 0, stream>>>(hf, hb, stats + 2*i,
                                                  poolp + (size_t)(i*2+0)*HH,
                                                  poolp + (size_t)(i*2+1)*HH,
                                                  coef + 12 + i*3, alive);
        readout_k<<<GG, HH, 0, stream>>>(hb, gstart, coef + 21 + (i+1)*3, reps + (size_t)(i+1)*GG*HH);
    }

    final_k<<<GG, HH, 0, stream>>>(reps, coef + 33, loW, lob, cW, cb, out);
}

// Round 4
// 763.091 us; speedup vs baseline: 2.7925x; 1.2500x over previous
//
#include <hip/hip_runtime.h>
#include <math.h>

#define NN 50000
#define EE 800000
#define GG 512
#define HH 128
#define LL 3
#define OUTC 10
#define THR 0.01f

typedef unsigned short u16;
typedef unsigned int u32;
typedef __attribute__((ext_vector_type(8))) short short8;
typedef __attribute__((ext_vector_type(4))) float f32x4;

__device__ __forceinline__ float elu_f(float x){ return x > 0.f ? x : (expf(x)-1.f); }
__device__ __forceinline__ u16 f2bf(float f){
    u32 u = __float_as_uint(f);
    return (u16)((u + 0x7fffu + ((u>>16)&1u)) >> 16);
}
__device__ __forceinline__ float bf2f(u16 b){ return __uint_as_float(((u32)b)<<16); }
__device__ __forceinline__ u32 pack2(float a, float b){
    return (u32)f2bf(a) | ((u32)f2bf(b)<<16);
}

// ---------------- setup kernels ----------------

__device__ void softmax_row(const float* in, float* out, int c){
    float m = in[0];
    for (int j=1;j<c;++j) m = fmaxf(m, in[j]);
    float s = 0.f;
    for (int j=0;j<c;++j){ float e = expf(in[j]-m); out[j]=e; s+=e; }
    for (int j=0;j<c;++j) out[j] /= s;
}

// coef layout: na[12] @0, pool[9] @12, ro[12] @21, la[3] @33
__global__ void prep_coef_k(const float* __restrict__ na, const float* __restrict__ pl,
                            const float* __restrict__ ro, const float* __restrict__ la,
                            float* __restrict__ coef){
    if (threadIdx.x != 0 || blockIdx.x != 0) return;
    for (int i=0;i<LL;++i)   softmax_row(na + i*4, coef + i*4, 4);
    for (int i=0;i<LL;++i)   softmax_row(pl + i*3, coef + 12 + i*3, 3);
    for (int i=0;i<LL+1;++i) softmax_row(ro + i*3, coef + 21 + i*3, 3);
    softmax_row(la, coef + 33, 3);
}

// Per-layer combined B stacks, bf16, TRANSPOSED to [n][k]:
// B0 = a1*W2+a2*W3+a3*W4 (h), B1 = a2*W3+a3*W5 (sagg), B2 = a1*W1 (isagg), B3 = a0*W0 (gagg)
__global__ __launch_bounds__(256) void prep_w_k(const float* __restrict__ gW,
                                                const float* __restrict__ lin1W,
                                                const float* __restrict__ coef,
                                                u16* __restrict__ Wc, u16* __restrict__ lin1t){
    int idx = blockIdx.x*256 + threadIdx.x;
    const int total = LL*4*16384;
    if (idx < total){
        int i = idx >> 16;
        int rem = idx & 65535;
        int p = rem >> 14;
        int j = rem & 16383;
        int n = j >> 7, k = j & 127;
        const float* W = gW + (size_t)i*6*16384;
        float a0=coef[i*4], a1=coef[i*4+1], a2=coef[i*4+2], a3=coef[i*4+3];
        int e = k*128 + n;
        float v;
        if (p==0)      v = a1*W[2*16384+e] + a2*W[3*16384+e] + a3*W[4*16384+e];
        else if (p==1) v = a2*W[3*16384+e] + a3*W[5*16384+e];
        else if (p==2) v = a1*W[1*16384+e];
        else           v = a0*W[0*16384+e];
        Wc[(size_t)(i*4+p)*16384 + n*128 + k] = f2bf(v);
    } else if (idx < total + 16384){
        int j = idx - total;
        int n = j >> 7, k = j & 127;
        lin1t[n*128 + k] = f2bf(lin1W[k*128 + n]);
    }
}

__global__ void x2bf_k(const float* __restrict__ x, u16* __restrict__ xb){
    int i = blockIdx.x*256 + threadIdx.x;
    if (i >= NN*HH/8) return;
    const float4* p = (const float4*)x + (size_t)i*2;
    float4 v0 = p[0], v1 = p[1];
    uint4 o;
    o.x = pack2(v0.x, v0.y); o.y = pack2(v0.z, v0.w);
    o.z = pack2(v1.x, v1.y); o.w = pack2(v1.z, v1.w);
    ((uint4*)xb)[i] = o;
}

__global__ void count_k(const int* __restrict__ dst, int* __restrict__ counts){
    int e = blockIdx.x*256 + threadIdx.x;
    if (e < EE) atomicAdd(&counts[dst[e]], 1);
}

__global__ void scan_k(const int* __restrict__ counts, int* __restrict__ row_ptr){
    __shared__ int part[256];
    __shared__ int pref[257];
    int t = threadIdx.x;
    const int chunk = (NN + 255) / 256;
    int b = t*chunk, e = b + chunk; if (e > NN) e = NN; if (b > NN) b = NN;
    int s = 0;
    for (int n=b;n<e;++n) s += counts[n];
    part[t] = s;
    __syncthreads();
    if (t == 0){
        int a = 0;
        for (int i=0;i<256;++i){ pref[i] = a; a += part[i]; }
        pref[256] = a;
    }
    __syncthreads();
    int run = pref[t];
    for (int n=b;n<e;++n){ row_ptr[n] = run; run += counts[n]; }
    if (t == 0) row_ptr[NN] = pref[256];
}

__global__ void copy_int_k(const int* __restrict__ a, int* __restrict__ b, int n){
    int i = blockIdx.x*256 + threadIdx.x;
    if (i < n) b[i] = a[i];
}

__global__ void initf_k(float* __restrict__ a, float v, int n){
    int i = blockIdx.x*256 + threadIdx.x;
    if (i < n) a[i] = v;
}

__global__ void fill_k(const int* __restrict__ src, const int* __restrict__ dst,
                       int* __restrict__ cursor, int* __restrict__ csr_src){
    int e = blockIdx.x*256 + threadIdx.x;
    if (e < EE){
        int p = atomicAdd(&cursor[dst[e]], 1);
        csr_src[p] = src[e];
    }
}

__global__ void gstart_k(const int* __restrict__ batch, int* __restrict__ gstart){
    int g = blockIdx.x*256 + threadIdx.x;
    if (g > GG) return;
    if (g == GG){ gstart[GG] = NN; return; }
    int lo = 0, hi = NN;
    while (lo < hi){
        int mid = (lo + hi) >> 1;
        if (batch[mid] < g) lo = mid + 1; else hi = mid;
    }
    gstart[g] = lo;
}

// ---------------- LDS-free MFMA GEMM ----------------
// C[M,128] = elu( sum_p A_p[M,128] @ B_p (+bias) ) -> bf16; FLAGS&1: also LN stats.
// A bf16 [row][k]; B bf16 transposed [n][k]. All fragment loads direct from global.
template<int FLAGS, int NP>
__global__ __launch_bounds__(256) void mm_k(
    const u16* __restrict__ A0, const u16* __restrict__ A1,
    const u16* __restrict__ A2, const u16* __restrict__ A3,
    const u16* __restrict__ Bb, const float* __restrict__ bias,
    u16* __restrict__ Cbf, double* __restrict__ stats, int M)
{
    int tid = threadIdx.x;
    int w = tid >> 6, l = tid & 63;
    int row0 = blockIdx.x * 128;
    int rbase = row0 + w*32 + (l & 15);
    int kq = l >> 4;
    const short8 zz = {0,0,0,0,0,0,0,0};

    f32x4 acc[2][8];
    #pragma unroll
    for (int rt=0;rt<2;++rt)
        #pragma unroll
        for (int ct=0;ct<8;++ct) acc[rt][ct] = (f32x4){0.f,0.f,0.f,0.f};

    const u16* Aps[4] = {A0, A1, A2, A3};
    #pragma unroll
    for (int p=0; p<NP; ++p){
        const u16* __restrict__ Ap = Aps[p];
        const u16* __restrict__ Bp = Bb + p*16384;
        #pragma unroll
        for (int ks=0; ks<4; ++ks){
            int ko = (ks*4 + kq)*8;
            short8 a[2], b[8];
            #pragma unroll
            for (int rt=0; rt<2; ++rt){
                int gr = rbase + rt*16;
                a[rt] = (gr < M) ? *(const short8*)(Ap + (size_t)gr*128 + ko) : zz;
            }
            #pragma unroll
            for (int ct=0; ct<8; ++ct)
                b[ct] = *(const short8*)(Bp + (ct*16 + (l&15))*128 + ko);
            #pragma unroll
            for (int rt=0; rt<2; ++rt)
                #pragma unroll
                for (int ct=0; ct<8; ++ct)
                    acc[rt][ct] = __builtin_amdgcn_mfma_f32_16x16x32_bf16(a[rt], b[ct], acc[rt][ct], 0, 0, 0);
        }
    }

    float ls = 0.f, lq = 0.f;
    float bcol[8];
    if constexpr (FLAGS & 2){
        #pragma unroll
        for (int ct=0; ct<8; ++ct) bcol[ct] = bias[ct*16 + (l&15)];
    }
    #pragma unroll
    for (int rt=0; rt<2; ++rt){
        #pragma unroll
        for (int i=0; i<4; ++i){
            int row = row0 + w*32 + rt*16 + (l>>4)*4 + i;
            if (row >= M) continue;
            #pragma unroll
            for (int ct=0; ct<8; ++ct){
                float v = acc[rt][ct][i];
                if constexpr (FLAGS & 2) v += bcol[ct];
                v = elu_f(v);
                Cbf[(size_t)row*128 + ct*16 + (l&15)] = f2bf(v);
                if constexpr (FLAGS & 1){ ls += v; lq = fmaf(v, v, lq); }
            }
        }
    }
    if constexpr (FLAGS & 1){
        double s = ls, q = lq;
        #pragma unroll
        for (int o=32;o>0;o>>=1){ s += __shfl_xor(s,o,64); q += __shfl_xor(q,o,64); }
        __shared__ double sw[4], qw[4];
        if (l == 0){ sw[w] = s; qw[w] = q; }
        __syncthreads();
        if (tid == 0){
            atomicAdd(&stats[0], sw[0]+sw[1]+sw[2]+sw[3]);
            atomicAdd(&stats[1], qw[0]+qw[1]+qw[2]+qw[3]);
        }
    }
}

// ---------------- per-layer graph kernels ----------------

// wave per node: deg = 1 + sum alive[nbr] (alive n), else 1e-6.
// ar2[n] = (alive, alive*rsqrt(deg)); invdeg[n] = 1/deg
__global__ __launch_bounds__(256) void deg2_k(const int* __restrict__ rp, const int* __restrict__ cs,
                                              const float* __restrict__ alive,
                                              float2* __restrict__ ar2, float* __restrict__ invdeg){
    int n = (blockIdx.x*256 + threadIdx.x) >> 6;
    int lane = threadIdx.x & 63;
    if (n >= NN) return;
    int e0 = rp[n], e1 = rp[n+1];
    float c = 0.f;
    for (int e = e0 + lane; e < e1; e += 64) c += alive[cs[e]];
    #pragma unroll
    for (int o=32;o>0;o>>=1) c += __shfl_xor(c, o, 64);
    if (lane == 0){
        float al = alive[n];
        float d = (al == 0.f) ? 1e-6f : fmaxf(1.f + c, 1e-6f);
        ar2[n] = make_float2(al, al * rsqrtf(d));
        invdeg[n] = 1.f / d;
    }
}

// wave per node, unroll-4 weighted gather (no branches in hot loop):
// sagg = sum w.x*h[s] + h[n]; isagg = sagg*invdeg[n]; gagg = rn*(sum w.y*h[s] + rn*h[n])
__global__ __launch_bounds__(256) void agg_k(const u16* __restrict__ h,
    const int* __restrict__ rp, const int* __restrict__ cs,
    const float2* __restrict__ ar2, const float* __restrict__ invdeg,
    u16* __restrict__ sagg, u16* __restrict__ isagg, u16* __restrict__ gagg){
    int n = (blockIdx.x*256 + threadIdx.x) >> 6;
    int lane = threadIdx.x & 63;
    if (n >= NN) return;
    float2 an = ar2[n];
    u32* so = (u32*)(sagg  + (size_t)n*HH);
    u32* io = (u32*)(isagg + (size_t)n*HH);
    u32* go = (u32*)(gagg  + (size_t)n*HH);
    if (an.x == 0.f){ so[lane]=0u; io[lane]=0u; go[lane]=0u; return; }
    float idg = invdeg[n];
    float rn  = an.y;
    int e0 = rp[n], e1 = rp[n+1];
    float sx=0.f, sy=0.f, gx=0.f, gy=0.f;
    for (int e = e0; e < e1; e += 4){
        int lastv = e1 - 1;
        int x1 = e+1 <= lastv ? e+1 : lastv;
        int x2 = e+2 <= lastv ? e+2 : lastv;
        int x3 = e+3 <= lastv ? e+3 : lastv;
        int s0 = cs[e], s1 = cs[x1], s2 = cs[x2], s3 = cs[x3];
        float2 w0 = ar2[s0], w1 = ar2[s1], w2 = ar2[s2], w3 = ar2[s3];
        if (e+1 > lastv){ w1.x = 0.f; w1.y = 0.f; }
        if (e+2 > lastv){ w2.x = 0.f; w2.y = 0.f; }
        if (e+3 > lastv){ w3.x = 0.f; w3.y = 0.f; }
        u32 h0 = *(const u32*)(h + (size_t)s0*HH + lane*2);
        u32 h1 = *(const u32*)(h + (size_t)s1*HH + lane*2);
        u32 h2 = *(const u32*)(h + (size_t)s2*HH + lane*2);
        u32 h3 = *(const u32*)(h + (size_t)s3*HH + lane*2);
        float ax, ay;
        ax = bf2f((u16)(h0 & 0xffffu)); ay = bf2f((u16)(h0 >> 16));
        sx = fmaf(w0.x, ax, sx); sy = fmaf(w0.x, ay, sy);
        gx = fmaf(w0.y, ax, gx); gy = fmaf(w0.y, ay, gy);
        ax = bf2f((u16)(h1 & 0xffffu)); ay = bf2f((u16)(h1 >> 16));
        sx = fmaf(w1.x, ax, sx); sy = fmaf(w1.x, ay, sy);
        gx = fmaf(w1.y, ax, gx); gy = fmaf(w1.y, ay, gy);
        ax = bf2f((u16)(h2 & 0xffffu)); ay = bf2f((u16)(h2 >> 16));
        sx = fmaf(w2.x, ax, sx); sy = fmaf(w2.x, ay, sy);
        gx = fmaf(w2.y, ax, gx); gy = fmaf(w2.y, ay, gy);
        ax = bf2f((u16)(h3 & 0xffffu)); ay = bf2f((u16)(h3 >> 16));
        sx = fmaf(w3.x, ax, sx); sy = fmaf(w3.x, ay, sy);
        gx = fmaf(w3.y, ax, gx); gy = fmaf(w3.y, ay, gy);
    }
    u32 hn = *(const u32*)(h + (size_t)n*HH + lane*2);
    float hx = bf2f((u16)(hn & 0xffffu)), hy = bf2f((u16)(hn >> 16));
    sx += hx; sy += hy;
    gx = fmaf(rn, hx, gx); gy = fmaf(rn, hy, gy);
    so[lane] = pack2(sx, sy);
    io[lane] = pack2(sx*idg, sy*idg);
    go[lane] = pack2(rn*gx, rn*gy);
}

// full-tensor LayerNorm + gate pooling; bf16 in/out (in place)
__global__ __launch_bounds__(256) void ln_pool_k(u16* __restrict__ hb,
                                                 const double* __restrict__ stats,
                                                 const float* __restrict__ p0,
                                                 const float* __restrict__ p1,
                                                 const float* __restrict__ pa,
                                                 float* __restrict__ alive){
    int n = (blockIdx.x*256 + threadIdx.x) >> 6;
    int lane = threadIdx.x & 63;
    if (n >= NN) return;
    const double tot = (double)NN * (double)HH;
    double m = stats[0] / tot;
    double var = stats[1] / tot - m*m;
    float mf = (float)m;
    float rs = rsqrtf((float)var + 1e-5f);
    u32 hv = ((u32*)(hb + (size_t)n*HH))[lane];
    float vx = (bf2f((u16)(hv & 0xffffu)) - mf) * rs;
    float vy = (bf2f((u16)(hv >> 16))    - mf) * rs;
    float2 q0 = ((const float2*)p0)[lane];
    float2 q1 = ((const float2*)p1)[lane];
    float d0 = vx*q0.x + vy*q0.y;
    float d1 = vx*q1.x + vy*q1.y;
    #pragma unroll
    for (int o=32;o>0;o>>=1){ d0 += __shfl_xor(d0,o,64); d1 += __shfl_xor(d1,o,64); }
    float g1 = 1.f/(1.f + expf(-d0));
    float g2 = tanhf(d1);
    float gate = pa[0]*g1 + pa[1]*g2 + pa[2];
    float keep = gate > THR ? 1.f : 0.f;
    float sc = gate*keep;
    ((u32*)(hb + (size_t)n*HH))[lane] = pack2(vx*sc, vy*sc);
    if (lane == 0 && keep == 0.f) alive[n] = 0.f;
}

// mixed readout per graph: w0*mean + w1*max + w2*sum; 256 threads = 2 row-halves
__global__ __launch_bounds__(256) void readout_k(const u16* __restrict__ h,
                                                 const int* __restrict__ gstart,
                                                 const float* __restrict__ w,
                                                 float* __restrict__ rep){
    int g = blockIdx.x;
    int t = threadIdx.x & 127, half = threadIdx.x >> 7;
    int beg = gstart[g], end = gstart[g+1];
    float sum = 0.f, mx = -INFINITY;
    for (int n = beg + half; n < end; n += 2){
        float v = bf2f(h[(size_t)n*HH + t]);
        sum += v;
        mx = fmaxf(mx, v);
    }
    __shared__ float ss[128], ms[128];
    if (half == 0){ ss[t] = sum; ms[t] = mx; }
    __syncthreads();
    if (half == 1){
        sum += ss[t];
        mx = fmaxf(mx, ms[t]);
        float cnt = (float)(end - beg);
        float mean = sum / fmaxf(cnt, 1.f);
        if (end <= beg) mx = 0.f;
        rep[(size_t)g*HH + t] = w[0]*mean + w[1]*mx + w[2]*sum;
    }
}

__global__ __launch_bounds__(128) void final_k(const float* __restrict__ reps,
                                               const float* __restrict__ la,
                                               const float* __restrict__ loW,
                                               const float* __restrict__ lob,
                                               const float* __restrict__ cW,
                                               const float* __restrict__ cb,
                                               float* __restrict__ out){
    int g = blockIdx.x, t = threadIdx.x;
    float r0 = reps[(size_t)(0*GG+g)*HH + t];
    float r1 = reps[(size_t)(1*GG+g)*HH + t];
    float r2 = reps[(size_t)(2*GG+g)*HH + t];
    float r3 = reps[(size_t)(3*GG+g)*HH + t];
    float s = r0+r1+r2+r3;
    float mean = 0.25f*s;
    float mx = fmaxf(fmaxf(r0,r1), fmaxf(r2,r3));
    float z = la[0]*elu_f(s) + la[1]*elu_f(mean) + la[2]*elu_f(mx);
    __shared__ float zs[HH];
    zs[t] = z;
    __syncthreads();
    float a = lob[t];
    for (int k=0;k<HH;++k) a = fmaf(zs[k], loW[(size_t)k*HH + t], a);
    float z2 = elu_f(a);
    __shared__ float z2s[HH];
    z2s[t] = z2;
    __syncthreads();
    __shared__ float lg[OUTC];
    if (t < OUTC){
        float acc = cb[t];
        for (int k=0;k<HH;++k) acc = fmaf(z2s[k], cW[(size_t)k*OUTC + t], acc);
        lg[t] = acc;
    }
    __syncthreads();
    if (t == 0){
        float m = lg[0];
        for (int o=1;o<OUTC;++o) m = fmaxf(m, lg[o]);
        float se = 0.f;
        for (int o=0;o<OUTC;++o) se += expf(lg[o]-m);
        float lse = m + logf(se);
        for (int o=0;o<OUTC;++o) out[(size_t)g*OUTC + o] = lg[o] - lse;
    }
}

// ---------------- host launch ----------------

extern "C" void kernel_launch(void* const* d_in, const int* in_sizes, int n_in,
                              void* d_out, int out_size, void* d_ws, size_t ws_size,
                              hipStream_t stream){
    const float* x     = (const float*)d_in[0];
    const int*   ei    = (const int*)d_in[1];
    const int*   batch = (const int*)d_in[2];
    const float* l1W   = (const float*)d_in[3];
    const float* l1b   = (const float*)d_in[4];
    const float* gW    = (const float*)d_in[5];
    const float* poolp = (const float*)d_in[6];
    const float* loW   = (const float*)d_in[7];
    const float* lob   = (const float*)d_in[8];
    const float* cW    = (const float*)d_in[9];
    const float* cb    = (const float*)d_in[10];
    const float* nalog = (const float*)d_in[11];
    const float* pllog = (const float*)d_in[12];
    const float* rolog = (const float*)d_in[13];
    const float* lalog = (const float*)d_in[14];
    float* out = (float*)d_out;

    char* wsb = (char*)d_ws;
    size_t off = 0;
    auto alloc = [&](size_t bytes)->char* {
        char* p = wsb + off;
        off += (bytes + 255) & ~(size_t)255;
        return p;
    };
    u16*   hb     = (u16*)alloc(sizeof(u16)*(size_t)NN*HH);
    u16*   xb     = (u16*)alloc(sizeof(u16)*(size_t)NN*HH);
    u16*   sagg   = (u16*)alloc(sizeof(u16)*(size_t)NN*HH);
    u16*   isagg  = (u16*)alloc(sizeof(u16)*(size_t)NN*HH);
    u16*   gagg   = (u16*)alloc(sizeof(u16)*(size_t)NN*HH);
    u16*   Wc     = (u16*)alloc(sizeof(u16)*(size_t)LL*4*HH*HH);
    u16*   lin1t  = (u16*)alloc(sizeof(u16)*HH*HH);
    int*   row_ptr= (int*)alloc(sizeof(int)*(NN+1));
    int*   counts = (int*)alloc(sizeof(int)*NN);
    int*   cursor = (int*)alloc(sizeof(int)*NN);
    int*   csr_src= (int*)alloc(sizeof(int)*EE);
    float2* ar2   = (float2*)alloc(sizeof(float2)*NN);
    float* invdeg = (float*)alloc(sizeof(float)*NN);
    float* alive  = (float*)alloc(sizeof(float)*NN);
    int*   gstart = (int*)alloc(sizeof(int)*(GG+1));
    float* reps   = (float*)alloc(sizeof(float)*(size_t)(LL+1)*GG*HH);
    float* coef   = (float*)alloc(sizeof(float)*64);
    double* stats = (double*)alloc(sizeof(double)*2*LL);

    const int* srcp = ei;
    const int* dstp = ei + EE;

    hipMemsetAsync(counts, 0, sizeof(int)*NN, stream);
    hipMemsetAsync(stats, 0, sizeof(double)*2*LL, stream);

    prep_coef_k<<<1, 64, 0, stream>>>(nalog, pllog, rolog, lalog, coef);
    prep_w_k<<<(LL*4*16384 + 16384 + 255)/256, 256, 0, stream>>>(gW, l1W, coef, Wc, lin1t);
    count_k<<<(EE + 255)/256, 256, 0, stream>>>(dstp, counts);
    scan_k<<<1, 256, 0, stream>>>(counts, row_ptr);
    copy_int_k<<<(NN + 255)/256, 256, 0, stream>>>(row_ptr, cursor, NN);
    fill_k<<<(EE + 255)/256, 256, 0, stream>>>(srcp, dstp, cursor, csr_src);
    gstart_k<<<(GG + 256)/256, 256, 0, stream>>>(batch, gstart);
    initf_k<<<(NN + 255)/256, 256, 0, stream>>>(alive, 1.f, NN);
    x2bf_k<<<(NN*HH/8 + 255)/256, 256, 0, stream>>>(x, xb);

    const int gemm_blocks = (NN + 127)/128;

    // h = elu(x @ lin1_W + b) -> bf16
    mm_k<2,1><<<gemm_blocks, 256, 0, stream>>>(xb, nullptr, nullptr, nullptr,
                                               lin1t, l1b, hb, nullptr, NN);
    readout_k<<<GG, 256, 0, stream>>>(hb, gstart, coef + 21, reps);

    for (int i=0;i<LL;++i){
        deg2_k<<<(NN + 3)/4, 256, 0, stream>>>(row_ptr, csr_src, alive, ar2, invdeg);
        agg_k<<<(NN + 3)/4, 256, 0, stream>>>(hb, row_ptr, csr_src, ar2, invdeg,
                                              sagg, isagg, gagg);
        mm_k<1,4><<<gemm_blocks, 256, 0, stream>>>(hb, sagg, isagg, gagg,
                                                   Wc + (size_t)i*4*16384, nullptr,
                                                   hb, stats + 2*i, NN);
        ln_pool_k<<<(NN + 3)/4, 256, 0, stream>>>(hb, stats + 2*i,
                                                  poolp + (size_t)(i*2+0)*HH,
                                                  poolp + (size_t)(i*2+1)*HH,
                                                  coef + 12 + i*3, alive);
        readout_k<<<GG, 256, 0, stream>>>(hb, gstart, coef + 21 + (i+1)*3, reps + (size_t)(i+1)*GG*HH);
    }

    final_k<<<GG, HH, 0, stream>>>(reps, coef + 33, loW, lob, cW, cb, out);
}

// Round 5
// 678.287 us; speedup vs baseline: 3.1417x; 1.1250x over previous
//
#include <hip/hip_runtime.h>
#include <math.h>

#define NN 50000
#define EE 800000
#define GG 512
#define HH 128
#define LL 3
#define OUTC 10
#define THR 0.01f

typedef unsigned short u16;
typedef unsigned int u32;
typedef __attribute__((ext_vector_type(8))) short short8;
typedef __attribute__((ext_vector_type(4))) float f32x4;

__device__ __forceinline__ float elu_f(float x){ return x > 0.f ? x : (expf(x)-1.f); }
__device__ __forceinline__ u16 f2bf(float f){
    u32 u = __float_as_uint(f);
    return (u16)((u + 0x7fffu + ((u>>16)&1u)) >> 16);
}
__device__ __forceinline__ float bf2f(u16 b){ return __uint_as_float(((u32)b)<<16); }
__device__ __forceinline__ u32 pack2(float a, float b){
    return (u32)f2bf(a) | ((u32)f2bf(b)<<16);
}

// ---------------- setup kernels ----------------

__device__ void softmax_row(const float* in, float* out, int c){
    float m = in[0];
    for (int j=1;j<c;++j) m = fmaxf(m, in[j]);
    float s = 0.f;
    for (int j=0;j<c;++j){ float e = expf(in[j]-m); out[j]=e; s+=e; }
    for (int j=0;j<c;++j) out[j] /= s;
}

// coef layout: na[12] @0, pool[9] @12, ro[12] @21, la[3] @33
__global__ void prep_coef_k(const float* __restrict__ na, const float* __restrict__ pl,
                            const float* __restrict__ ro, const float* __restrict__ la,
                            float* __restrict__ coef){
    if (threadIdx.x != 0 || blockIdx.x != 0) return;
    for (int i=0;i<LL;++i)   softmax_row(na + i*4, coef + i*4, 4);
    for (int i=0;i<LL;++i)   softmax_row(pl + i*3, coef + 12 + i*3, 3);
    for (int i=0;i<LL+1;++i) softmax_row(ro + i*3, coef + 21 + i*3, 3);
    softmax_row(la, coef + 33, 3);
}

// Per-layer combined B stacks, bf16, TRANSPOSED to [n][k]:
// B0 = a1*W2+a2*W3+a3*W4 (h), B1 = a2*W3+a3*W5 (sagg), B2 = a1*W1 (isagg), B3 = a0*W0 (gagg)
__global__ __launch_bounds__(256) void prep_w_k(const float* __restrict__ gW,
                                                const float* __restrict__ lin1W,
                                                const float* __restrict__ coef,
                                                u16* __restrict__ Wc, u16* __restrict__ lin1t){
    int idx = blockIdx.x*256 + threadIdx.x;
    const int total = LL*4*16384;
    if (idx < total){
        int i = idx >> 16;
        int rem = idx & 65535;
        int p = rem >> 14;
        int j = rem & 16383;
        int n = j >> 7, k = j & 127;
        const float* W = gW + (size_t)i*6*16384;
        float a0=coef[i*4], a1=coef[i*4+1], a2=coef[i*4+2], a3=coef[i*4+3];
        int e = k*128 + n;
        float v;
        if (p==0)      v = a1*W[2*16384+e] + a2*W[3*16384+e] + a3*W[4*16384+e];
        else if (p==1) v = a2*W[3*16384+e] + a3*W[5*16384+e];
        else if (p==2) v = a1*W[1*16384+e];
        else           v = a0*W[0*16384+e];
        Wc[(size_t)(i*4+p)*16384 + n*128 + k] = f2bf(v);
    } else if (idx < total + 16384){
        int j = idx - total;
        int n = j >> 7, k = j & 127;
        lin1t[n*128 + k] = f2bf(lin1W[k*128 + n]);
    }
}

__global__ void x2bf_k(const float* __restrict__ x, u16* __restrict__ xb){
    int i = blockIdx.x*256 + threadIdx.x;
    if (i >= NN*HH/8) return;
    const float4* p = (const float4*)x + (size_t)i*2;
    float4 v0 = p[0], v1 = p[1];
    uint4 o;
    o.x = pack2(v0.x, v0.y); o.y = pack2(v0.z, v0.w);
    o.z = pack2(v1.x, v1.y); o.w = pack2(v1.z, v1.w);
    ((uint4*)xb)[i] = o;
}

__global__ void count_k(const int* __restrict__ dst, int* __restrict__ counts){
    int e = blockIdx.x*256 + threadIdx.x;
    if (e < EE) atomicAdd(&counts[dst[e]], 1);
}

// ---- hierarchical prefix scan over counts[NN] ----
// scan1: 49 blocks x 256 threads x 4 elems; writes within-block EXCLUSIVE prefix
// into pre[] and per-block totals into bsum[].
__global__ __launch_bounds__(256) void scan1_k(const int* __restrict__ counts,
                                               int* __restrict__ pre, int* __restrict__ bsum){
    int b = blockIdx.x, t = threadIdx.x;
    int base = b*1024 + t*4;
    int4 v = make_int4(0,0,0,0);
    if (base + 3 < NN) v = *(const int4*)(counts + base);
    else {
        int* pv = (int*)&v;
        #pragma unroll
        for (int j=0;j<4;++j) pv[j] = (base+j < NN) ? counts[base+j] : 0;
    }
    int s0 = v.x, s1 = s0+v.y, s2 = s1+v.z, s3 = s2+v.w;   // thread-local inclusive
    int lane = t & 63, w = t >> 6;
    int incl = s3;
    #pragma unroll
    for (int o=1;o<64;o<<=1){
        int u = __shfl_up(incl, o, 64);
        if (lane >= o) incl += u;
    }
    __shared__ int wsum[4];
    if (lane == 63) wsum[w] = incl;
    __syncthreads();
    int woff = 0;
    #pragma unroll
    for (int i=0;i<4;++i) if (i < w) woff += wsum[i];
    int excl = woff + incl - s3;
    int4 o4 = make_int4(excl, excl+s0, excl+s1, excl+s2);
    if (base + 3 < NN) *(int4*)(pre + base) = o4;
    else {
        int* po = (int*)&o4;
        for (int j=0;j<4;++j) if (base+j < NN) pre[base+j] = po[j];
    }
    if (t == 255) bsum[b] = woff + incl;
}

// scan3: each block adds sum(bsum[0..b-1]) and writes row_ptr + cursor.
__global__ __launch_bounds__(256) void scan3_k(const int* __restrict__ pre,
                                               const int* __restrict__ bsum,
                                               int* __restrict__ row_ptr, int* __restrict__ cursor){
    int b = blockIdx.x, t = threadIdx.x;
    __shared__ int boff_s;
    if (t < 64){
        int v = (t < b) ? bsum[t] : 0;
        #pragma unroll
        for (int o=32;o>0;o>>=1) v += __shfl_down(v, o, 64);
        if (t == 0) boff_s = v;
    }
    __syncthreads();
    int boff = boff_s;
    int base = b*1024;
    #pragma unroll
    for (int j=0;j<4;++j){
        int i = base + j*256 + t;
        if (i < NN){
            int r = pre[i] + boff;
            row_ptr[i] = r;
            cursor[i] = r;
        }
    }
    if (b == 0 && t == 0) row_ptr[NN] = EE;
}

__global__ void initf_k(float* __restrict__ a, float v, int n){
    int i = blockIdx.x*256 + threadIdx.x;
    if (i < n) a[i] = v;
}

__global__ void fill_k(const int* __restrict__ src, const int* __restrict__ dst,
                       int* __restrict__ cursor, int* __restrict__ csr_src){
    int e = blockIdx.x*256 + threadIdx.x;
    if (e < EE){
        int p = atomicAdd(&cursor[dst[e]], 1);
        csr_src[p] = src[e];
    }
}

__global__ void gstart_k(const int* __restrict__ batch, int* __restrict__ gstart){
    int g = blockIdx.x*256 + threadIdx.x;
    if (g > GG) return;
    if (g == GG){ gstart[GG] = NN; return; }
    int lo = 0, hi = NN;
    while (lo < hi){
        int mid = (lo + hi) >> 1;
        if (batch[mid] < g) lo = mid + 1; else hi = mid;
    }
    gstart[g] = lo;
}

// ---------------- LDS-free MFMA GEMM ----------------
// C[M,128] = elu( sum_p A_p[M,128] @ B_p (+bias) ) -> bf16; FLAGS&1: also LN stats.
// A bf16 [row][k]; B bf16 transposed [n][k]. All fragment loads direct from global.
template<int FLAGS, int NP>
__global__ __launch_bounds__(256) void mm_k(
    const u16* __restrict__ A0, const u16* __restrict__ A1,
    const u16* __restrict__ A2, const u16* __restrict__ A3,
    const u16* __restrict__ Bb, const float* __restrict__ bias,
    u16* __restrict__ Cbf, double* __restrict__ stats, int M)
{
    int tid = threadIdx.x;
    int w = tid >> 6, l = tid & 63;
    int row0 = blockIdx.x * 128;
    int rbase = row0 + w*32 + (l & 15);
    int kq = l >> 4;
    const short8 zz = {0,0,0,0,0,0,0,0};

    f32x4 acc[2][8];
    #pragma unroll
    for (int rt=0;rt<2;++rt)
        #pragma unroll
        for (int ct=0;ct<8;++ct) acc[rt][ct] = (f32x4){0.f,0.f,0.f,0.f};

    const u16* Aps[4] = {A0, A1, A2, A3};
    #pragma unroll
    for (int p=0; p<NP; ++p){
        const u16* __restrict__ Ap = Aps[p];
        const u16* __restrict__ Bp = Bb + p*16384;
        #pragma unroll
        for (int ks=0; ks<4; ++ks){
            int ko = (ks*4 + kq)*8;
            short8 a[2], b[8];
            #pragma unroll
            for (int rt=0; rt<2; ++rt){
                int gr = rbase + rt*16;
                a[rt] = (gr < M) ? *(const short8*)(Ap + (size_t)gr*128 + ko) : zz;
            }
            #pragma unroll
            for (int ct=0; ct<8; ++ct)
                b[ct] = *(const short8*)(Bp + (ct*16 + (l&15))*128 + ko);
            #pragma unroll
            for (int rt=0; rt<2; ++rt)
                #pragma unroll
                for (int ct=0; ct<8; ++ct)
                    acc[rt][ct] = __builtin_amdgcn_mfma_f32_16x16x32_bf16(a[rt], b[ct], acc[rt][ct], 0, 0, 0);
        }
    }

    float ls = 0.f, lq = 0.f;
    float bcol[8];
    if constexpr (FLAGS & 2){
        #pragma unroll
        for (int ct=0; ct<8; ++ct) bcol[ct] = bias[ct*16 + (l&15)];
    }
    #pragma unroll
    for (int rt=0; rt<2; ++rt){
        #pragma unroll
        for (int i=0; i<4; ++i){
            int row = row0 + w*32 + rt*16 + (l>>4)*4 + i;
            if (row >= M) continue;
            #pragma unroll
            for (int ct=0; ct<8; ++ct){
                float v = acc[rt][ct][i];
                if constexpr (FLAGS & 2) v += bcol[ct];
                v = elu_f(v);
                Cbf[(size_t)row*128 + ct*16 + (l&15)] = f2bf(v);
                if constexpr (FLAGS & 1){ ls += v; lq = fmaf(v, v, lq); }
            }
        }
    }
    if constexpr (FLAGS & 1){
        double s = ls, q = lq;
        #pragma unroll
        for (int o=32;o>0;o>>=1){ s += __shfl_xor(s,o,64); q += __shfl_xor(q,o,64); }
        __shared__ double sw[4], qw[4];
        if (l == 0){ sw[w] = s; qw[w] = q; }
        __syncthreads();
        if (tid == 0){
            atomicAdd(&stats[0], sw[0]+sw[1]+sw[2]+sw[3]);
            atomicAdd(&stats[1], qw[0]+qw[1]+qw[2]+qw[3]);
        }
    }
}

// ---------------- per-layer graph kernels ----------------

// wave per node: deg = 1 + sum alive[nbr] (alive n), else 1e-6.
// ar2[n] = (alive, alive*rsqrt(deg)); invdeg[n] = 1/deg
__global__ __launch_bounds__(256) void deg2_k(const int* __restrict__ rp, const int* __restrict__ cs,
                                              const float* __restrict__ alive,
                                              float2* __restrict__ ar2, float* __restrict__ invdeg){
    int n = (blockIdx.x*256 + threadIdx.x) >> 6;
    int lane = threadIdx.x & 63;
    if (n >= NN) return;
    int e0 = rp[n], e1 = rp[n+1];
    float c = 0.f;
    for (int e = e0 + lane; e < e1; e += 64) c += alive[cs[e]];
    #pragma unroll
    for (int o=32;o>0;o>>=1) c += __shfl_xor(c, o, 64);
    if (lane == 0){
        float al = alive[n];
        float d = (al == 0.f) ? 1e-6f : fmaxf(1.f + c, 1e-6f);
        ar2[n] = make_float2(al, al * rsqrtf(d));
        invdeg[n] = 1.f / d;
    }
}

// wave per node, unroll-4 weighted gather (no branches in hot loop):
// sagg = sum w.x*h[s] + h[n]; isagg = sagg*invdeg[n]; gagg = rn*(sum w.y*h[s] + rn*h[n])
__global__ __launch_bounds__(256) void agg_k(const u16* __restrict__ h,
    const int* __restrict__ rp, const int* __restrict__ cs,
    const float2* __restrict__ ar2, const float* __restrict__ invdeg,
    u16* __restrict__ sagg, u16* __restrict__ isagg, u16* __restrict__ gagg){
    int n = (blockIdx.x*256 + threadIdx.x) >> 6;
    int lane = threadIdx.x & 63;
    if (n >= NN) return;
    float2 an = ar2[n];
    u32* so = (u32*)(sagg  + (size_t)n*HH);
    u32* io = (u32*)(isagg + (size_t)n*HH);
    u32* go = (u32*)(gagg  + (size_t)n*HH);
    if (an.x == 0.f){ so[lane]=0u; io[lane]=0u; go[lane]=0u; return; }
    float idg = invdeg[n];
    float rn  = an.y;
    int e0 = rp[n], e1 = rp[n+1];
    float sx=0.f, sy=0.f, gx=0.f, gy=0.f;
    for (int e = e0; e < e1; e += 4){
        int lastv = e1 - 1;
        int x1 = e+1 <= lastv ? e+1 : lastv;
        int x2 = e+2 <= lastv ? e+2 : lastv;
        int x3 = e+3 <= lastv ? e+3 : lastv;
        int s0 = cs[e], s1 = cs[x1], s2 = cs[x2], s3 = cs[x3];
        float2 w0 = ar2[s0], w1 = ar2[s1], w2 = ar2[s2], w3 = ar2[s3];
        if (e+1 > lastv){ w1.x = 0.f; w1.y = 0.f; }
        if (e+2 > lastv){ w2.x = 0.f; w2.y = 0.f; }
        if (e+3 > lastv){ w3.x = 0.f; w3.y = 0.f; }
        u32 h0 = *(const u32*)(h + (size_t)s0*HH + lane*2);
        u32 h1 = *(const u32*)(h + (size_t)s1*HH + lane*2);
        u32 h2 = *(const u32*)(h + (size_t)s2*HH + lane*2);
        u32 h3 = *(const u32*)(h + (size_t)s3*HH + lane*2);
        float ax, ay;
        ax = bf2f((u16)(h0 & 0xffffu)); ay = bf2f((u16)(h0 >> 16));
        sx = fmaf(w0.x, ax, sx); sy = fmaf(w0.x, ay, sy);
        gx = fmaf(w0.y, ax, gx); gy = fmaf(w0.y, ay, gy);
        ax = bf2f((u16)(h1 & 0xffffu)); ay = bf2f((u16)(h1 >> 16));
        sx = fmaf(w1.x, ax, sx); sy = fmaf(w1.x, ay, sy);
        gx = fmaf(w1.y, ax, gx); gy = fmaf(w1.y, ay, gy);
        ax = bf2f((u16)(h2 & 0xffffu)); ay = bf2f((u16)(h2 >> 16));
        sx = fmaf(w2.x, ax, sx); sy = fmaf(w2.x, ay, sy);
        gx = fmaf(w2.y, ax, gx); gy = fmaf(w2.y, ay, gy);
        ax = bf2f((u16)(h3 & 0xffffu)); ay = bf2f((u16)(h3 >> 16));
        sx = fmaf(w3.x, ax, sx); sy = fmaf(w3.x, ay, sy);
        gx = fmaf(w3.y, ax, gx); gy = fmaf(w3.y, ay, gy);
    }
    u32 hn = *(const u32*)(h + (size_t)n*HH + lane*2);
    float hx = bf2f((u16)(hn & 0xffffu)), hy = bf2f((u16)(hn >> 16));
    sx += hx; sy += hy;
    gx = fmaf(rn, hx, gx); gy = fmaf(rn, hy, gy);
    so[lane] = pack2(sx, sy);
    io[lane] = pack2(sx*idg, sy*idg);
    go[lane] = pack2(rn*gx, rn*gy);
}

// full-tensor LayerNorm + gate pooling; bf16 in/out (in place)
__global__ __launch_bounds__(256) void ln_pool_k(u16* __restrict__ hb,
                                                 const double* __restrict__ stats,
                                                 const float* __restrict__ p0,
                                                 const float* __restrict__ p1,
                                                 const float* __restrict__ pa,
                                                 float* __restrict__ alive){
    int n = (blockIdx.x*256 + threadIdx.x) >> 6;
    int lane = threadIdx.x & 63;
    if (n >= NN) return;
    const double tot = (double)NN * (double)HH;
    double m = stats[0] / tot;
    double var = stats[1] / tot - m*m;
    float mf = (float)m;
    float rs = rsqrtf((float)var + 1e-5f);
    u32 hv = ((u32*)(hb + (size_t)n*HH))[lane];
    float vx = (bf2f((u16)(hv & 0xffffu)) - mf) * rs;
    float vy = (bf2f((u16)(hv >> 16))    - mf) * rs;
    float2 q0 = ((const float2*)p0)[lane];
    float2 q1 = ((const float2*)p1)[lane];
    float d0 = vx*q0.x + vy*q0.y;
    float d1 = vx*q1.x + vy*q1.y;
    #pragma unroll
    for (int o=32;o>0;o>>=1){ d0 += __shfl_xor(d0,o,64); d1 += __shfl_xor(d1,o,64); }
    float g1 = 1.f/(1.f + expf(-d0));
    float g2 = tanhf(d1);
    float gate = pa[0]*g1 + pa[1]*g2 + pa[2];
    float keep = gate > THR ? 1.f : 0.f;
    float sc = gate*keep;
    ((u32*)(hb + (size_t)n*HH))[lane] = pack2(vx*sc, vy*sc);
    if (lane == 0 && keep == 0.f) alive[n] = 0.f;
}

// mixed readout per graph: w0*mean + w1*max + w2*sum; 256 threads = 2 row-halves
__global__ __launch_bounds__(256) void readout_k(const u16* __restrict__ h,
                                                 const int* __restrict__ gstart,
                                                 const float* __restrict__ w,
                                                 float* __restrict__ rep){
    int g = blockIdx.x;
    int t = threadIdx.x & 127, half = threadIdx.x >> 7;
    int beg = gstart[g], end = gstart[g+1];
    float sum = 0.f, mx = -INFINITY;
    for (int n = beg + half; n < end; n += 2){
        float v = bf2f(h[(size_t)n*HH + t]);
        sum += v;
        mx = fmaxf(mx, v);
    }
    __shared__ float ss[128], ms[128];
    if (half == 0){ ss[t] = sum; ms[t] = mx; }
    __syncthreads();
    if (half == 1){
        sum += ss[t];
        mx = fmaxf(mx, ms[t]);
        float cnt = (float)(end - beg);
        float mean = sum / fmaxf(cnt, 1.f);
        if (end <= beg) mx = 0.f;
        rep[(size_t)g*HH + t] = w[0]*mean + w[1]*mx + w[2]*sum;
    }
}

__global__ __launch_bounds__(128) void final_k(const float* __restrict__ reps,
                                               const float* __restrict__ la,
                                               const float* __restrict__ loW,
                                               const float* __restrict__ lob,
                                               const float* __restrict__ cW,
                                               const float* __restrict__ cb,
                                               float* __restrict__ out){
    int g = blockIdx.x, t = threadIdx.x;
    float r0 = reps[(size_t)(0*GG+g)*HH + t];
    float r1 = reps[(size_t)(1*GG+g)*HH + t];
    float r2 = reps[(size_t)(2*GG+g)*HH + t];
    float r3 = reps[(size_t)(3*GG+g)*HH + t];
    float s = r0+r1+r2+r3;
    float mean = 0.25f*s;
    float mx = fmaxf(fmaxf(r0,r1), fmaxf(r2,r3));
    float z = la[0]*elu_f(s) + la[1]*elu_f(mean) + la[2]*elu_f(mx);
    __shared__ float zs[HH];
    zs[t] = z;
    __syncthreads();
    float a = lob[t];
    for (int k=0;k<HH;++k) a = fmaf(zs[k], loW[(size_t)k*HH + t], a);
    float z2 = elu_f(a);
    __shared__ float z2s[HH];
    z2s[t] = z2;
    __syncthreads();
    __shared__ float lg[OUTC];
    if (t < OUTC){
        float acc = cb[t];
        for (int k=0;k<HH;++k) acc = fmaf(z2s[k], cW[(size_t)k*OUTC + t], acc);
        lg[t] = acc;
    }
    __syncthreads();
    if (t == 0){
        float m = lg[0];
        for (int o=1;o<OUTC;++o) m = fmaxf(m, lg[o]);
        float se = 0.f;
        for (int o=0;o<OUTC;++o) se += expf(lg[o]-m);
        float lse = m + logf(se);
        for (int o=0;o<OUTC;++o) out[(size_t)g*OUTC + o] = lg[o] - lse;
    }
}

// ---------------- host launch ----------------

extern "C" void kernel_launch(void* const* d_in, const int* in_sizes, int n_in,
                              void* d_out, int out_size, void* d_ws, size_t ws_size,
                              hipStream_t stream){
    const float* x     = (const float*)d_in[0];
    const int*   ei    = (const int*)d_in[1];
    const int*   batch = (const int*)d_in[2];
    const float* l1W   = (const float*)d_in[3];
    const float* l1b   = (const float*)d_in[4];
    const float* gW    = (const float*)d_in[5];
    const float* poolp = (const float*)d_in[6];
    const float* loW   = (const float*)d_in[7];
    const float* lob   = (const float*)d_in[8];
    const float* cW    = (const float*)d_in[9];
    const float* cb    = (const float*)d_in[10];
    const float* nalog = (const float*)d_in[11];
    const float* pllog = (const float*)d_in[12];
    const float* rolog = (const float*)d_in[13];
    const float* lalog = (const float*)d_in[14];
    float* out = (float*)d_out;

    char* wsb = (char*)d_ws;
    size_t off = 0;
    auto alloc = [&](size_t bytes)->char* {
        char* p = wsb + off;
        off += (bytes + 255) & ~(size_t)255;
        return p;
    };
    u16*   hb     = (u16*)alloc(sizeof(u16)*(size_t)NN*HH);
    u16*   xb     = (u16*)alloc(sizeof(u16)*(size_t)NN*HH);
    u16*   sagg   = (u16*)alloc(sizeof(u16)*(size_t)NN*HH);
    u16*   isagg  = (u16*)alloc(sizeof(u16)*(size_t)NN*HH);
    u16*   gagg   = (u16*)alloc(sizeof(u16)*(size_t)NN*HH);
    u16*   Wc     = (u16*)alloc(sizeof(u16)*(size_t)LL*4*HH*HH);
    u16*   lin1t  = (u16*)alloc(sizeof(u16)*HH*HH);
    int*   row_ptr= (int*)alloc(sizeof(int)*(NN+1));
    int*   counts = (int*)alloc(sizeof(int)*NN);
    int*   cursor = (int*)alloc(sizeof(int)*NN);
    int*   pre    = (int*)alloc(sizeof(int)*NN);
    int*   bsum   = (int*)alloc(sizeof(int)*64);
    int*   csr_src= (int*)alloc(sizeof(int)*EE);
    float2* ar2   = (float2*)alloc(sizeof(float2)*NN);
    float* invdeg = (float*)alloc(sizeof(float)*NN);
    float* alive  = (float*)alloc(sizeof(float)*NN);
    int*   gstart = (int*)alloc(sizeof(int)*(GG+1));
    float* reps   = (float*)alloc(sizeof(float)*(size_t)(LL+1)*GG*HH);
    float* coef   = (float*)alloc(sizeof(float)*64);
    double* stats = (double*)alloc(sizeof(double)*2*LL);

    const int* srcp = ei;
    const int* dstp = ei + EE;

    hipMemsetAsync(counts, 0, sizeof(int)*NN, stream);
    hipMemsetAsync(stats, 0, sizeof(double)*2*LL, stream);

    const int SCAN_BLOCKS = (NN + 1023)/1024;   // 49

    prep_coef_k<<<1, 64, 0, stream>>>(nalog, pllog, rolog, lalog, coef);
    prep_w_k<<<(LL*4*16384 + 16384 + 255)/256, 256, 0, stream>>>(gW, l1W, coef, Wc, lin1t);
    count_k<<<(EE + 255)/256, 256, 0, stream>>>(dstp, counts);
    scan1_k<<<SCAN_BLOCKS, 256, 0, stream>>>(counts, pre, bsum);
    scan3_k<<<SCAN_BLOCKS, 256, 0, stream>>>(pre, bsum, row_ptr, cursor);
    fill_k<<<(EE + 255)/256, 256, 0, stream>>>(srcp, dstp, cursor, csr_src);
    gstart_k<<<(GG + 256)/256, 256, 0, stream>>>(batch, gstart);
    initf_k<<<(NN + 255)/256, 256, 0, stream>>>(alive, 1.f, NN);
    x2bf_k<<<(NN*HH/8 + 255)/256, 256, 0, stream>>>(x, xb);

    const int gemm_blocks = (NN + 127)/128;

    // h = elu(x @ lin1_W + b) -> bf16
    mm_k<2,1><<<gemm_blocks, 256, 0, stream>>>(xb, nullptr, nullptr, nullptr,
                                               lin1t, l1b, hb, nullptr, NN);
    readout_k<<<GG, 256, 0, stream>>>(hb, gstart, coef + 21, reps);

    for (int i=0;i<LL;++i){
        deg2_k<<<(NN + 3)/4, 256, 0, stream>>>(row_ptr, csr_src, alive, ar2, invdeg);
        agg_k<<<(NN + 3)/4, 256, 0, stream>>>(hb, row_ptr, csr_src, ar2, invdeg,
                                              sagg, isagg, gagg);
        mm_k<1,4><<<gemm_blocks, 256, 0, stream>>>(hb, sagg, isagg, gagg,
                                                   Wc + (size_t)i*4*16384, nullptr,
                                                   hb, stats + 2*i, NN);
        ln_pool_k<<<(NN + 3)/4, 256, 0, stream>>>(hb, stats + 2*i,
                                                  poolp + (size_t)(i*2+0)*HH,
                                                  poolp + (size_t)(i*2+1)*HH,
                                                  coef + 12 + i*3, alive);
        readout_k<<<GG, 256, 0, stream>>>(hb, gstart, coef + 21 + (i+1)*3, reps + (size_t)(i+1)*GG*HH);
    }

    final_k<<<GG, HH, 0, stream>>>(reps, coef + 33, loW, lob, cW, cb, out);
}